// Round 8
// baseline (237.121 us; speedup 1.0000x reference)
//
#include <hip/hip_runtime.h>
#include <hip/hip_bf16.h>
#include <cfloat>
#include <math.h>

#define EMBED 1024
#define NHEADS 16
#define DK 64
#define SEQL 2048
#define BATCH 2
#define NTOK 4096

// HW-established: inputs/outputs fp32; ws_size = 64MB; MFMA layouts verified
// (rounds 3-15, absmax 0.0156): A/B frag [m=lane&15][k=quad*8+j]; C/D
// col=lane&15,row=quad*4+rg.
// Structure rules (each from a measured failure):
//  - r10: direct-from-global MFMA operands expose full L2/HBM latency. NEVER.
//  - r11/r12 (fault x2): global_load_lds across a barrier crashes; only
//    issue-then-drain is safe (drain = the next barrier, none in between).
//    Plain global loads to REGISTERS across barriers are safe (attn pref()).
//  - r14 (spill): >16 prefetch VGPRs/thread in GEMMs spills acc.
//  - LDS pitch must be a multiple of 8 ushorts (b128 alignment).
//  - r8: 128-key attn tile spills; r13: full K-split attn = net wash.
// r16: attn CU load-balance fix (qt = (y&8) ? x : 31-x).
// qkv history (the 2-phase plateau, ~480 TF on this K=1024 shape):
//  r17/r18: [128][64] LDS (128B pitch) -> conflicts 9.57M, 64.6us.
//  r19: pitch-32 -> conflicts 3.28M but VGPR 136 crossed 128 cliff, 70.5us.
//  r20: launch_bounds(256,4) -> VGPR 64, occ 24%, 54.3us (BEST of family).
//  r21: BK=32 stage-ahead ping-pong -> 57.8us NULL (__syncthreads drains
//       vmcnt(0); overlap window ~100cyc << HBM latency). Source-level
//       pipelining on 2-barrier structures is null; counted-vmcnt escape is
//       r11/r12-forbidden. qkv FROZEN at r20 config.
// r22: attn single-barrier K/V double-buffer. Staging source is regs
//  (prefetched a full tile ahead), so per kt: ONE barrier, then ds_write
//  buf^1 overlaps MFMA+softmax on buf. Barriers/kt 2->1. LDS 27->45KB
//  (4->3 blocks/CU) — mechanism-vs-occupancy experiment.
// r23/r24: r6 & r7 benches were GPUAcquisitionTimeout (infra) — resubmitting
//  r22 unchanged to get its measurement.
// ws: xb(8) Wqkv(6) Wob(2) Qg(8) Kg(8) Vt(8) CTXb(8) = 48MB.

typedef __bf16 bf16x8 __attribute__((ext_vector_type(8)));
typedef float floatx4 __attribute__((ext_vector_type(4)));

__device__ __forceinline__ unsigned short f2bf(float f) {
    union { __hip_bfloat16 b; unsigned short u; } c;
    c.b = __float2bfloat16(f);   // RNE
    return c.u;
}

// async global->LDS, 16B per lane; lds base wave-uniform, lane i -> base+16*i.
// MUST be drained by the immediately following barrier (r11/r12 fault).
__device__ __forceinline__ void async16(void* lds, const void* g) {
    __builtin_amdgcn_global_load_lds(
        (const __attribute__((address_space(1))) unsigned int*)g,
        (__attribute__((address_space(3))) unsigned int*)lds,
        16, 0, 0);
}

// ---------------- pre-pass: fp32 -> bf16 convert + QKV weight pack -----------
__global__ __launch_bounds__(256) void convert_pack(
    const float* __restrict__ x,  const float* __restrict__ Wq,
    const float* __restrict__ Wk, const float* __restrict__ Wv,
    const float* __restrict__ Wo,
    unsigned short* __restrict__ xb, unsigned short* __restrict__ Wqkv,
    unsigned short* __restrict__ Wob)
{
    const int XG = 1048576, WG = 262144;   // float4 groups
    int g = blockIdx.x * 256 + threadIdx.x;
    const float4* s; ushort4* d;
    if (g < XG)               { s = (const float4*)x  + g;                d = (ushort4*)xb   + g; }
    else if (g < XG + WG)     { s = (const float4*)Wq + (g - XG);         d = (ushort4*)Wqkv + (g - XG); }
    else if (g < XG + 2 * WG) { s = (const float4*)Wk + (g - XG - WG);    d = (ushort4*)Wqkv + (g - XG); }
    else if (g < XG + 3 * WG) { s = (const float4*)Wv + (g - XG - 2*WG);  d = (ushort4*)Wqkv + (g - XG); }
    else                      { s = (const float4*)Wo + (g - XG - 3*WG);  d = (ushort4*)Wob  + (g - XG - 3*WG); }
    float4 v = *s;
    *d = (ushort4){f2bf(v.x), f2bf(v.y), f2bf(v.z), f2bf(v.w)};
}

// ---------------- fused QKV GEMM, 128x128 tile, BK=64, pitch-32 LDS ----------
// r20-frozen: 4 waves in 2x2; each wave owns a 64x64 output sub-tile
// (acc[4][4]). Wave column range (wc*64) == one head => RoPE in-register.
// __launch_bounds__(256,4) caps regs at 128 (VGPR 64 measured, occ 24%).
__global__ __launch_bounds__(256, 4) void qkv_gemm(
    const unsigned short* __restrict__ xb, const unsigned short* __restrict__ Wqkv,
    const float* __restrict__ bq, const float* __restrict__ bk, const float* __restrict__ bv,
    const float* __restrict__ cosT, const float* __restrict__ sinT,
    unsigned short* __restrict__ Qg, unsigned short* __restrict__ Kg,
    unsigned short* __restrict__ Vt)
{
    __shared__ __align__(16) unsigned short SM[16384];  // 32 KB
    unsigned short* As0 = SM;            // [128][32]
    unsigned short* As1 = SM + 4096;     // [128][32]
    unsigned short* Bs0 = SM + 8192;     // [128][32]
    unsigned short* Bs1 = SM + 12288;    // [128][32]

    const int t = threadIdx.x, lane = t & 63, w = t >> 6;
    const int quad = lane >> 4, lrow = lane & 15;
    const int wr = w >> 1, wc = w & 1;
    const int m0 = blockIdx.y * 128;     // tokens
    const int n0 = blockIdx.x * 128;     // out col (0..2944)
    const int srow = lane >> 2;          // 0..15: row within a 16-row group
    const int scol = (lane & 3) * 8;     // 16B chunk col (ushorts): 0,8,16,24

    floatx4 acc[4][4];
    #pragma unroll
    for (int i = 0; i < 4; i++)
        #pragma unroll
        for (int j = 0; j < 4; j++) acc[i][j] = (floatx4){0.f,0.f,0.f,0.f};

    for (int k0 = 0; k0 < EMBED; k0 += 64) {
        __syncthreads();
        #pragma unroll
        for (int c = 0; c < 2; c++) {
            // wave w stages rows [w*32, w*32+32) of A and of B (16 rows/call)
            const unsigned short* as = xb
                + (size_t)(m0 + w * 32 + c * 16 + srow) * EMBED + k0 + scol;
            async16(&As0[(w * 32 + c * 16) * 32], as);
            async16(&As1[(w * 32 + c * 16) * 32], as + 32);
            const unsigned short* bs = Wqkv
                + (size_t)(n0 + w * 32 + c * 16 + srow) * EMBED + k0 + scol;
            async16(&Bs0[(w * 32 + c * 16) * 32], bs);
            async16(&Bs1[(w * 32 + c * 16) * 32], bs + 32);
        }
        __syncthreads();

        #pragma unroll
        for (int ks = 0; ks < 2; ks++) {
            const unsigned short* Ab = ks ? As1 : As0;
            const unsigned short* Bb = ks ? Bs1 : Bs0;
            // B frags resident (16 VGPR); A frags fetched one at a time
            // (live frag regs 8 -> 5) so the 128-reg cap doesn't spill.
            bf16x8 bfB[4];
            #pragma unroll
            for (int j = 0; j < 4; j++)
                bfB[j] = *reinterpret_cast<const bf16x8*>(
                    &Bb[(wc * 64 + j * 16 + lrow) * 32 + quad * 8]);
            #pragma unroll
            for (int i = 0; i < 4; i++) {
                bf16x8 af = *reinterpret_cast<const bf16x8*>(
                    &Ab[(wr * 64 + i * 16 + lrow) * 32 + quad * 8]);
                #pragma unroll
                for (int j = 0; j < 4; j++)
                    acc[i][j] = __builtin_amdgcn_mfma_f32_16x16x32_bf16(af, bfB[j], acc[i][j], 0, 0, 0);
            }
        }
    }

    const int mat   = n0 >> 10;           // 0=Q 1=K 2=V (BN=128 divides 1024)
    const int nloc  = n0 & 1023;
    const int hbase = nloc >> 6;          // first head of this block (even)
    const int bb    = m0 >> 11;
    const int s0    = m0 & (SEQL - 1);

    if (mat == 2) {
        unsigned short* T2 = SM;          // [64][136] = 8704 elems (17.4 KB)
        #pragma unroll
        for (int hh = 0; hh < 2; hh++) {
            __syncthreads();              // staging/previous-pass reads done
            if (wc == hh) {
                #pragma unroll
                for (int j = 0; j < 4; j++) {
                    int d = j * 16 + lrow;
                    float bvv = bv[nloc + hh * 64 + d];
                    #pragma unroll
                    for (int i = 0; i < 4; i++) {
                        int tok = wr * 64 + i * 16 + quad * 4;
                        *(ushort4*)&T2[d * 136 + tok] = (ushort4){
                            f2bf(acc[i][j][0] + bvv), f2bf(acc[i][j][1] + bvv),
                            f2bf(acc[i][j][2] + bvv), f2bf(acc[i][j][3] + bvv)};
                    }
                }
            }
            __syncthreads();
            int d = t >> 2, tg = (t & 3) * 32;
            unsigned short* dst = Vt
                + ((size_t)(bb * NHEADS + hbase + hh) * DK + d) * SEQL + s0 + tg;
            #pragma unroll
            for (int c = 0; c < 32; c += 8)
                *(uint4*)(dst + c) = *(const uint4*)&T2[d * 136 + tg + c];
        }
    } else {
        unsigned short* T = SM;           // [128][72] = 9216 elems (18.4 KB)
        const float* bias = (mat == 0) ? bq : bk;
        unsigned short* Og = (mat == 0) ? Qg : Kg;
        #pragma unroll
        for (int hh = 0; hh < 2; hh++) {
            __syncthreads();
            if (wc == hh) {
                // RoPE in-register: partner element d^32 is acc[i][j^2], same lane.
                #pragma unroll
                for (int j = 0; j < 4; j++) {
                    int d = j * 16 + lrow;          // col within head
                    float cb = bias[nloc + hh * 64 + d];
                    float pb = bias[nloc + hh * 64 + (d ^ 32)];
                    float sgn = (d < 32) ? -1.0f : 1.0f;
                    #pragma unroll
                    for (int i = 0; i < 4; i++)
                        #pragma unroll
                        for (int rg = 0; rg < 4; rg++) {
                            int tok = wr * 64 + i * 16 + quad * 4 + rg;
                            int s = s0 + tok;
                            float cv = cosT[s * DK + d];
                            float sv = sinT[s * DK + d];
                            float val = (acc[i][j][rg] + cb) * cv
                                      + sgn * (acc[i][j ^ 2][rg] + pb) * sv;
                            T[tok * 72 + d] = f2bf(val);
                        }
                }
            }
            __syncthreads();
            int tok = t >> 1, dh = (t & 1) * 32;
            unsigned short* dst = Og
                + ((size_t)(bb * NHEADS + hbase + hh) * SEQL + s0 + tok) * DK + dh;
            #pragma unroll
            for (int c = 0; c < 32; c += 8)
                *(uint4*)(dst + c) = *(const uint4*)&T[tok * 72 + dh + c];
        }
    }
}

// ---------------- unpaired MFMA causal flash attention ----------------------
// r22: single-barrier K/V double-buffer. Per kt: ONE __syncthreads, then
// ds_write of NEXT tile (from regs, prefetched a full tile ahead) overlaps
// the MFMA+softmax on the current buffer.
//  RAW: buf[cur] written in iter kt-1 body (or prologue), visible after this
//       iter's top barrier.
//  WAR: buf[cur^1] readers (iter kt-1, when it was 'cur') finished before
//       this barrier.
// Block = one (b,h,64-row q-tile); wave w owns q-rows [w*16,w*16+16). No-max
// softmax. qt mapping r16: co-resident blocks get complementary qt.
#define KP 72

__global__ __launch_bounds__(256) void attn_mfma(
    const unsigned short* __restrict__ Qg, const unsigned short* __restrict__ Kg,
    const unsigned short* __restrict__ Vt, unsigned short* __restrict__ CTX)
{
    __shared__ __align__(16) unsigned short Ks[2][64 * KP];   // 18.4 KB
    __shared__ __align__(16) unsigned short Vs[2][64 * KP];   // 18.4 KB
    __shared__ __align__(16) unsigned short Ps[64 * KP];      //  9.2 KB

    const int QT_MAX = SEQL / 64 - 1;              // 31
    const int qt = (blockIdx.y & 8) ? blockIdx.x : (QT_MAX - blockIdx.x);
    const int h = blockIdx.y, b = blockIdx.z;
    const int t = threadIdx.x;
    const int lane = t & 63, w = t >> 6;
    const int quad = lane >> 4, lrow = lane & 15;
    const int q0 = qt * 64;

    const unsigned short* Qh = Qg + (size_t)(b * NHEADS + h) * SEQL * DK;
    const unsigned short* Kh = Kg + (size_t)(b * NHEADS + h) * SEQL * DK;
    const unsigned short* Vh = Vt + (size_t)(b * NHEADS + h) * DK * SEQL;

    bf16x8 aq[2];
    #pragma unroll
    for (int ks = 0; ks < 2; ks++)
        aq[ks] = *(const bf16x8*)(Qh + (size_t)(q0 + w * 16 + lrow) * DK + quad * 8 + ks * 32);

    floatx4 of[4];
    float l[4] = {0,0,0,0};
    #pragma unroll
    for (int jd = 0; jd < 4; jd++) of[jd] = (floatx4){0,0,0,0};

    unsigned short* Pw = Ps + w * 16 * KP;     // wave-private P (16 x 64)

    const int r0 = t >> 3, c8 = (t & 7) * 8;
    uint4 pk0, pk1, pv0, pv1;
    auto pref = [&](int k0) {                  // plain loads to regs (safe
        pk0 = *(const uint4*)(Kh + (size_t)(k0 + r0) * DK + c8);      // across
        pk1 = *(const uint4*)(Kh + (size_t)(k0 + r0 + 32) * DK + c8); // barriers)
        pv0 = *(const uint4*)(Vh + (size_t)r0 * SEQL + k0 + c8);
        pv1 = *(const uint4*)(Vh + (size_t)(r0 + 32) * SEQL + k0 + c8);
    };
    auto stolds = [&](int buf) {               // regs -> LDS tile
        *(uint4*)&Ks[buf][r0 * KP + c8]        = pk0;
        *(uint4*)&Ks[buf][(r0 + 32) * KP + c8] = pk1;
        *(uint4*)&Vs[buf][r0 * KP + c8]        = pv0;
        *(uint4*)&Vs[buf][(r0 + 32) * KP + c8] = pv1;
    };

    // prologue: tile 0 into buf0 (pre-barrier writes are fine: disjoint rows,
    // visibility established by the first in-loop barrier); prefetch tile 1.
    pref(0);
    stolds(0);
    if (qt >= 1) pref(64);

    int cur = 0;
    for (int kt = 0; kt <= qt; kt++) {
        const int k0 = kt * 64;
        __syncthreads();                       // buf[cur] ready; buf[cur^1] free
        if (kt + 1 <= qt) {
            stolds(cur ^ 1);                   // overlaps with compute below
            if (kt + 2 <= qt) pref(k0 + 128);
        }

        floatx4 sc[4];
        #pragma unroll
        for (int j = 0; j < 4; j++) sc[j] = (floatx4){0,0,0,0};
        #pragma unroll
        for (int ks = 0; ks < 2; ks++)
            #pragma unroll
            for (int j = 0; j < 4; j++) {
                bf16x8 kb = *reinterpret_cast<const bf16x8*>(
                    &Ks[cur][(j * 16 + lrow) * KP + quad * 8 + ks * 32]);
                sc[j] = __builtin_amdgcn_mfma_f32_16x16x32_bf16(aq[ks], kb, sc[j], 0, 0, 0);
            }

        const bool diag = (kt == qt);
        #pragma unroll
        for (int rg = 0; rg < 4; rg++) {
            int row = q0 + w * 16 + quad * 4 + rg;
            float lacc = 0.f;
            #pragma unroll
            for (int j = 0; j < 4; j++) {
                float pval = __expf(sc[j][rg] * 0.125f);
                if (diag && (k0 + j * 16 + lrow) > row) pval = 0.f;
                Pw[(quad * 4 + rg) * KP + j * 16 + lrow] = f2bf(pval);
                lacc += pval;
            }
            l[rg] += lacc;
        }
        #pragma unroll
        for (int ks = 0; ks < 2; ks++) {
            bf16x8 pa = *reinterpret_cast<const bf16x8*>(&Pw[lrow * KP + quad * 8 + ks * 32]);
            #pragma unroll
            for (int jd = 0; jd < 4; jd++) {
                bf16x8 vb = *reinterpret_cast<const bf16x8*>(
                    &Vs[cur][(jd * 16 + lrow) * KP + quad * 8 + ks * 32]);
                of[jd] = __builtin_amdgcn_mfma_f32_16x16x32_bf16(pa, vb, of[jd], 0, 0, 0);
            }
        }
        cur ^= 1;
    }

    #pragma unroll
    for (int rg = 0; rg < 4; rg++) {
        float lv = l[rg];
        #pragma unroll
        for (int off = 1; off < 16; off <<= 1) lv += __shfl_xor(lv, off);
        float inv = 1.0f / lv;
        int row = q0 + w * 16 + quad * 4 + rg;
        unsigned short* Cr = CTX + ((size_t)(b * NHEADS + h) * SEQL + row) * DK;
        #pragma unroll
        for (int jd = 0; jd < 4; jd++) Cr[jd * 16 + lrow] = f2bf(of[jd][rg] * inv);
    }
}

// ---------------- O-projection GEMM, 128x64 tile, BK=64 (r9-proven) ----------
__global__ __launch_bounds__(256) void o_gemm(
    const unsigned short* __restrict__ Ag,   // CTX [b][h][s][d] bf16
    const unsigned short* __restrict__ Bg,   // Wob [1024][1024] bf16
    const float* __restrict__ bias, float* __restrict__ C)
{
    __shared__ __align__(16) unsigned short SM[12288];  // 24 KB
    unsigned short* As0 = SM;
    unsigned short* As1 = SM + 4096;
    unsigned short* Bs0 = SM + 8192;
    unsigned short* Bs1 = SM + 10240;

    const int t = threadIdx.x, lane = t & 63, wave = t >> 6;
    const int quad = lane >> 4, lrow = lane & 15;
    const int m0 = blockIdx.y * 128, n0 = blockIdx.x * 64;
    const int srow = lane >> 2;
    const int scol = (lane & 3) * 8;

    floatx4 acc[2][4];
    #pragma unroll
    for (int i = 0; i < 2; i++)
        #pragma unroll
        for (int j = 0; j < 4; j++) acc[i][j] = (floatx4){0.f,0.f,0.f,0.f};

    for (int k0 = 0; k0 < EMBED; k0 += 64) {
        const int hh = k0 >> 6;   // head for this K-slice
        __syncthreads();
        #pragma unroll
        for (int c = 0; c < 2; c++) {
            int tok = m0 + wave * 32 + c * 16 + srow;
            const unsigned short* as = Ag
                + ((size_t)((tok >> 11) * NHEADS + hh) * SEQL + (tok & (SEQL - 1))) * DK + scol;
            async16(&As0[wave * 1024 + c * 512], as);
            async16(&As1[wave * 1024 + c * 512], as + 32);
        }
        const unsigned short* bs = Bg + (size_t)(n0 + wave * 16 + srow) * EMBED + k0 + scol;
        async16(&Bs0[wave * 512], bs);
        async16(&Bs1[wave * 512], bs + 32);
        __syncthreads();

        #pragma unroll
        for (int ks = 0; ks < 2; ks++) {
            const unsigned short* Ab = ks ? As1 : As0;
            const unsigned short* Bb = ks ? Bs1 : Bs0;
            bf16x8 af[2], bfB[4];
            #pragma unroll
            for (int i = 0; i < 2; i++)
                af[i] = *reinterpret_cast<const bf16x8*>(&Ab[(wave * 32 + i * 16 + lrow) * 32 + quad * 8]);
            #pragma unroll
            for (int j = 0; j < 4; j++)
                bfB[j] = *reinterpret_cast<const bf16x8*>(&Bb[(j * 16 + lrow) * 32 + quad * 8]);
            #pragma unroll
            for (int i = 0; i < 2; i++)
                #pragma unroll
                for (int j = 0; j < 4; j++)
                    acc[i][j] = __builtin_amdgcn_mfma_f32_16x16x32_bf16(af[i], bfB[j], acc[i][j], 0, 0, 0);
        }
    }

    #pragma unroll
    for (int i = 0; i < 2; i++)
        #pragma unroll
        for (int rg = 0; rg < 4; rg++) {
            int row_g = m0 + wave * 32 + i * 16 + quad * 4 + rg;
            #pragma unroll
            for (int j = 0; j < 4; j++) {
                int col_g = n0 + j * 16 + lrow;
                C[(size_t)row_g * EMBED + col_g] = acc[i][j][rg] + bias[col_g];
            }
        }
}

// ---------------- launch ----------------
extern "C" void kernel_launch(void* const* d_in, const int* in_sizes, int n_in,
                              void* d_out, int out_size, void* d_ws, size_t ws_size,
                              hipStream_t stream) {
    const float* x    = (const float*)d_in[0];
    const float* cosT = (const float*)d_in[2];
    const float* sinT = (const float*)d_in[3];
    const float* Wq = (const float*)d_in[4];  const float* bq = (const float*)d_in[5];
    const float* Wk = (const float*)d_in[6];  const float* bk = (const float*)d_in[7];
    const float* Wv = (const float*)d_in[8];  const float* bv = (const float*)d_in[9];
    const float* Wo = (const float*)d_in[10]; const float* bo = (const float*)d_in[11];

    const size_t MB = 1024 * 1024;
    char* ws = (char*)d_ws;
    unsigned short* xb   = (unsigned short*)(ws);            //  8 MB
    unsigned short* Wqkv = (unsigned short*)(ws +  8 * MB);  //  6 MB
    unsigned short* Wob  = (unsigned short*)(ws + 14 * MB);  //  2 MB
    unsigned short* Qg   = (unsigned short*)(ws + 16 * MB);  //  8 MB [b][h][s][d]
    unsigned short* Kg   = (unsigned short*)(ws + 24 * MB);  //  8 MB [b][h][s][d]
    unsigned short* Vt   = (unsigned short*)(ws + 32 * MB);  //  8 MB [b][h][d][s]
    unsigned short* CTXb = (unsigned short*)(ws + 40 * MB);  //  8 MB [b][h][s][d]

    convert_pack<<<8192, 256, 0, stream>>>(x, Wq, Wk, Wv, Wo, xb, Wqkv, Wob);

    dim3 qkv_grid(3 * EMBED / 128, NTOK / 128);   // (24, 32) = 768
    qkv_gemm<<<qkv_grid, 256, 0, stream>>>(xb, Wqkv, bq, bk, bv, cosT, sinT, Qg, Kg, Vt);

    dim3 attn_grid(SEQL / 64, NHEADS, BATCH);     // (32, 16, 2) = 1024
    attn_mfma<<<attn_grid, 256, 0, stream>>>(Qg, Kg, Vt, CTXb);

    dim3 o_grid(EMBED / 64, NTOK / 128);          // (16, 32) = 512
    o_gemm<<<o_grid, 256, 0, stream>>>(CTXb, Wob, bo, (float*)d_out);
}

// Round 10
// 211.478 us; speedup vs baseline: 1.1213x; 1.1213x over previous
//
#include <hip/hip_runtime.h>
#include <hip/hip_bf16.h>
#include <cfloat>
#include <math.h>

#define EMBED 1024
#define NHEADS 16
#define DK 64
#define SEQL 2048
#define BATCH 2
#define NTOK 4096

// HW-established: inputs/outputs fp32; ws_size = 64MB; MFMA layouts verified
// (rounds 3-15, absmax 0.0156): A/B frag [m=lane&15][k=quad*8+j]; C/D
// col=lane&15,row=quad*4+rg.
// Structure rules (each from a measured failure):
//  - r10: direct-from-global MFMA operands expose full L2/HBM latency. NEVER.
//  - r11/r12 (fault x2): global_load_lds across a barrier crashes; only
//    issue-then-drain is safe (drain = the next barrier, none in between).
//    Plain global loads to REGISTERS across barriers are safe (attn pref()).
//  - r14 (spill): >16 prefetch VGPRs/thread in GEMMs spills acc.
//  - LDS pitch must be a multiple of 8 ushorts (b128 alignment).
//  - r8: 128-key attn tile spills; r13: full K-split attn = net wash.
// qkv history (the 2-phase plateau, ~480 TF on this K=1024 shape):
//  r19: pitch-32 conflicts 3.28M but VGPR 136 crossed 128 cliff, 70.5us.
//  r20: launch_bounds(256,4) -> VGPR 64, occ 24%, 54.3us (BEST). FROZEN.
//  r21: BK=32 stage-ahead ping-pong -> NULL (barrier drains vmcnt(0)).
// attn history:
//  r16: 2-barrier single-buffer, 4-wave QBLK=64, qt=(y&8)?x:31-x balance.
//       <53us (never in top-5 at the 214us total).
//  r22: single-barrier K/V dbuf -> 66.2us REGRESSION. LDS 45KB -> 3 blocks/CU,
//       occ 17%, MfmaUtil 10.4. attn is OCCUPANCY-bound; resident blocks rule.
//       Counters: FETCH 62.6MB (K/V re-fetched 2.6x), VALUBusy 26 >> Mfma 10.
//  r25: QBLK=128 via 8-wave/512-thread blocks, r16 structure. K/V tile staged
//       once serves 128 q-rows: staging+barriers per work halve; FETCH ~45MB.
//       LDS 36.8KB -> 2 blocks x 8 waves = 16 waves/CU (same as r16).
//       Unconditional causal mask (~3% tile waste). Balance: co-resident
//       (id,id+256) = b-flip -> st = b ? x : 15-x -> every CU 34 loop-tiles.
//  r26 (this round): r9 bench was GPUAcquisitionTimeout (infra) — resubmit
//       r25 unchanged to get its measurement.
// ws: xb(8) Wqkv(6) Wob(2) Qg(8) Kg(8) Vt(8) CTXb(8) = 48MB.

typedef __bf16 bf16x8 __attribute__((ext_vector_type(8)));
typedef float floatx4 __attribute__((ext_vector_type(4)));

__device__ __forceinline__ unsigned short f2bf(float f) {
    union { __hip_bfloat16 b; unsigned short u; } c;
    c.b = __float2bfloat16(f);   // RNE
    return c.u;
}

// async global->LDS, 16B per lane; lds base wave-uniform, lane i -> base+16*i.
// MUST be drained by the immediately following barrier (r11/r12 fault).
__device__ __forceinline__ void async16(void* lds, const void* g) {
    __builtin_amdgcn_global_load_lds(
        (const __attribute__((address_space(1))) unsigned int*)g,
        (__attribute__((address_space(3))) unsigned int*)lds,
        16, 0, 0);
}

// ---------------- pre-pass: fp32 -> bf16 convert + QKV weight pack -----------
__global__ __launch_bounds__(256) void convert_pack(
    const float* __restrict__ x,  const float* __restrict__ Wq,
    const float* __restrict__ Wk, const float* __restrict__ Wv,
    const float* __restrict__ Wo,
    unsigned short* __restrict__ xb, unsigned short* __restrict__ Wqkv,
    unsigned short* __restrict__ Wob)
{
    const int XG = 1048576, WG = 262144;   // float4 groups
    int g = blockIdx.x * 256 + threadIdx.x;
    const float4* s; ushort4* d;
    if (g < XG)               { s = (const float4*)x  + g;                d = (ushort4*)xb   + g; }
    else if (g < XG + WG)     { s = (const float4*)Wq + (g - XG);         d = (ushort4*)Wqkv + (g - XG); }
    else if (g < XG + 2 * WG) { s = (const float4*)Wk + (g - XG - WG);    d = (ushort4*)Wqkv + (g - XG); }
    else if (g < XG + 3 * WG) { s = (const float4*)Wv + (g - XG - 2*WG);  d = (ushort4*)Wqkv + (g - XG); }
    else                      { s = (const float4*)Wo + (g - XG - 3*WG);  d = (ushort4*)Wob  + (g - XG - 3*WG); }
    float4 v = *s;
    *d = (ushort4){f2bf(v.x), f2bf(v.y), f2bf(v.z), f2bf(v.w)};
}

// ---------------- fused QKV GEMM, 128x128 tile, BK=64, pitch-32 LDS ----------
// r20-frozen: 4 waves in 2x2; each wave owns a 64x64 output sub-tile
// (acc[4][4]). Wave column range (wc*64) == one head => RoPE in-register.
// __launch_bounds__(256,4) caps regs at 128 (VGPR 64 measured, occ 24%).
__global__ __launch_bounds__(256, 4) void qkv_gemm(
    const unsigned short* __restrict__ xb, const unsigned short* __restrict__ Wqkv,
    const float* __restrict__ bq, const float* __restrict__ bk, const float* __restrict__ bv,
    const float* __restrict__ cosT, const float* __restrict__ sinT,
    unsigned short* __restrict__ Qg, unsigned short* __restrict__ Kg,
    unsigned short* __restrict__ Vt)
{
    __shared__ __align__(16) unsigned short SM[16384];  // 32 KB
    unsigned short* As0 = SM;            // [128][32]
    unsigned short* As1 = SM + 4096;     // [128][32]
    unsigned short* Bs0 = SM + 8192;     // [128][32]
    unsigned short* Bs1 = SM + 12288;    // [128][32]

    const int t = threadIdx.x, lane = t & 63, w = t >> 6;
    const int quad = lane >> 4, lrow = lane & 15;
    const int wr = w >> 1, wc = w & 1;
    const int m0 = blockIdx.y * 128;     // tokens
    const int n0 = blockIdx.x * 128;     // out col (0..2944)
    const int srow = lane >> 2;          // 0..15: row within a 16-row group
    const int scol = (lane & 3) * 8;     // 16B chunk col (ushorts): 0,8,16,24

    floatx4 acc[4][4];
    #pragma unroll
    for (int i = 0; i < 4; i++)
        #pragma unroll
        for (int j = 0; j < 4; j++) acc[i][j] = (floatx4){0.f,0.f,0.f,0.f};

    for (int k0 = 0; k0 < EMBED; k0 += 64) {
        __syncthreads();
        #pragma unroll
        for (int c = 0; c < 2; c++) {
            // wave w stages rows [w*32, w*32+32) of A and of B (16 rows/call)
            const unsigned short* as = xb
                + (size_t)(m0 + w * 32 + c * 16 + srow) * EMBED + k0 + scol;
            async16(&As0[(w * 32 + c * 16) * 32], as);
            async16(&As1[(w * 32 + c * 16) * 32], as + 32);
            const unsigned short* bs = Wqkv
                + (size_t)(n0 + w * 32 + c * 16 + srow) * EMBED + k0 + scol;
            async16(&Bs0[(w * 32 + c * 16) * 32], bs);
            async16(&Bs1[(w * 32 + c * 16) * 32], bs + 32);
        }
        __syncthreads();

        #pragma unroll
        for (int ks = 0; ks < 2; ks++) {
            const unsigned short* Ab = ks ? As1 : As0;
            const unsigned short* Bb = ks ? Bs1 : Bs0;
            // B frags resident (16 VGPR); A frags fetched one at a time
            // (live frag regs 8 -> 5) so the 128-reg cap doesn't spill.
            bf16x8 bfB[4];
            #pragma unroll
            for (int j = 0; j < 4; j++)
                bfB[j] = *reinterpret_cast<const bf16x8*>(
                    &Bb[(wc * 64 + j * 16 + lrow) * 32 + quad * 8]);
            #pragma unroll
            for (int i = 0; i < 4; i++) {
                bf16x8 af = *reinterpret_cast<const bf16x8*>(
                    &Ab[(wr * 64 + i * 16 + lrow) * 32 + quad * 8]);
                #pragma unroll
                for (int j = 0; j < 4; j++)
                    acc[i][j] = __builtin_amdgcn_mfma_f32_16x16x32_bf16(af, bfB[j], acc[i][j], 0, 0, 0);
            }
        }
    }

    const int mat   = n0 >> 10;           // 0=Q 1=K 2=V (BN=128 divides 1024)
    const int nloc  = n0 & 1023;
    const int hbase = nloc >> 6;          // first head of this block (even)
    const int bb    = m0 >> 11;
    const int s0    = m0 & (SEQL - 1);

    if (mat == 2) {
        unsigned short* T2 = SM;          // [64][136] = 8704 elems (17.4 KB)
        #pragma unroll
        for (int hh = 0; hh < 2; hh++) {
            __syncthreads();              // staging/previous-pass reads done
            if (wc == hh) {
                #pragma unroll
                for (int j = 0; j < 4; j++) {
                    int d = j * 16 + lrow;
                    float bvv = bv[nloc + hh * 64 + d];
                    #pragma unroll
                    for (int i = 0; i < 4; i++) {
                        int tok = wr * 64 + i * 16 + quad * 4;
                        *(ushort4*)&T2[d * 136 + tok] = (ushort4){
                            f2bf(acc[i][j][0] + bvv), f2bf(acc[i][j][1] + bvv),
                            f2bf(acc[i][j][2] + bvv), f2bf(acc[i][j][3] + bvv)};
                    }
                }
            }
            __syncthreads();
            int d = t >> 2, tg = (t & 3) * 32;
            unsigned short* dst = Vt
                + ((size_t)(bb * NHEADS + hbase + hh) * DK + d) * SEQL + s0 + tg;
            #pragma unroll
            for (int c = 0; c < 32; c += 8)
                *(uint4*)(dst + c) = *(const uint4*)&T2[d * 136 + tg + c];
        }
    } else {
        unsigned short* T = SM;           // [128][72] = 9216 elems (18.4 KB)
        const float* bias = (mat == 0) ? bq : bk;
        unsigned short* Og = (mat == 0) ? Qg : Kg;
        #pragma unroll
        for (int hh = 0; hh < 2; hh++) {
            __syncthreads();
            if (wc == hh) {
                // RoPE in-register: partner element d^32 is acc[i][j^2], same lane.
                #pragma unroll
                for (int j = 0; j < 4; j++) {
                    int d = j * 16 + lrow;          // col within head
                    float cb = bias[nloc + hh * 64 + d];
                    float pb = bias[nloc + hh * 64 + (d ^ 32)];
                    float sgn = (d < 32) ? -1.0f : 1.0f;
                    #pragma unroll
                    for (int i = 0; i < 4; i++)
                        #pragma unroll
                        for (int rg = 0; rg < 4; rg++) {
                            int tok = wr * 64 + i * 16 + quad * 4 + rg;
                            int s = s0 + tok;
                            float cv = cosT[s * DK + d];
                            float sv = sinT[s * DK + d];
                            float val = (acc[i][j][rg] + cb) * cv
                                      + sgn * (acc[i][j ^ 2][rg] + pb) * sv;
                            T[tok * 72 + d] = f2bf(val);
                        }
                }
            }
            __syncthreads();
            int tok = t >> 1, dh = (t & 1) * 32;
            unsigned short* dst = Og
                + ((size_t)(bb * NHEADS + hbase + hh) * SEQL + s0 + tok) * DK + dh;
            #pragma unroll
            for (int c = 0; c < 32; c += 8)
                *(uint4*)(dst + c) = *(const uint4*)&T[tok * 72 + dh + c];
        }
    }
}

// ---------------- unpaired MFMA causal flash attention (r25: 8-wave) --------
// Block = one (b,h,128-row q-supertile), 512 threads. Wave w owns q-rows
// [st*128 + w*16, +16). r16 2-barrier single-buffer structure; K/V staged
// once per 128 q-rows. Unconditional causal mask (low waves' final tile is
// fully masked). st = b ? x : 15-x -> co-resident (id,id+256) blocks carry
// complementary st -> every CU runs exactly 34 loop-tiles.
#define KP 72

__global__ __launch_bounds__(512) void attn_mfma(
    const unsigned short* __restrict__ Qg, const unsigned short* __restrict__ Kg,
    const unsigned short* __restrict__ Vt, unsigned short* __restrict__ CTX)
{
    __shared__ __align__(16) unsigned short Ks[64 * KP];      //  9.2 KB
    __shared__ __align__(16) unsigned short Vs[64 * KP];      //  9.2 KB
    __shared__ __align__(16) unsigned short Ps[128 * KP];     // 18.4 KB

    const int ST_MAX = SEQL / 128 - 1;             // 15
    const int b = blockIdx.z, h = blockIdx.y;
    const int st = b ? blockIdx.x : (ST_MAX - blockIdx.x);
    const int t = threadIdx.x;
    const int lane = t & 63, w = t >> 6;           // w 0..7
    const int quad = lane >> 4, lrow = lane & 15;
    const int q0 = st * 128;
    const int qtmax = 2 * st + 1;

    const unsigned short* Qh = Qg + (size_t)(b * NHEADS + h) * SEQL * DK;
    const unsigned short* Kh = Kg + (size_t)(b * NHEADS + h) * SEQL * DK;
    const unsigned short* Vh = Vt + (size_t)(b * NHEADS + h) * DK * SEQL;

    bf16x8 aq[2];
    #pragma unroll
    for (int ks = 0; ks < 2; ks++)
        aq[ks] = *(const bf16x8*)(Qh + (size_t)(q0 + w * 16 + lrow) * DK + quad * 8 + ks * 32);

    floatx4 of[4];
    float l[4] = {0,0,0,0};
    #pragma unroll
    for (int jd = 0; jd < 4; jd++) of[jd] = (floatx4){0,0,0,0};

    unsigned short* Pw = Ps + w * 16 * KP;     // wave-private P (16 x 64)

    // 512 threads stage the 64x64 K and V tiles: 16B each.
    const int r0 = t >> 3, c8 = (t & 7) * 8;   // r0 0..63, c8 0..56
    uint4 pk0, pv0;
    auto pref = [&](int k0) {                  // plain loads to regs (safe
        pk0 = *(const uint4*)(Kh + (size_t)(k0 + r0) * DK + c8);   // across
        pv0 = *(const uint4*)(Vh + (size_t)r0 * SEQL + k0 + c8);   // barriers)
    };
    pref(0);

    for (int kt = 0; kt <= qtmax; kt++) {
        const int k0 = kt * 64;
        __syncthreads();                       // previous tile's reads done
        *(uint4*)&Ks[r0 * KP + c8] = pk0;
        *(uint4*)&Vs[r0 * KP + c8] = pv0;
        __syncthreads();                       // tile kt visible
        if (kt < qtmax) pref(k0 + 64);

        floatx4 sc[4];
        #pragma unroll
        for (int j = 0; j < 4; j++) sc[j] = (floatx4){0,0,0,0};
        #pragma unroll
        for (int ks = 0; ks < 2; ks++)
            #pragma unroll
            for (int j = 0; j < 4; j++) {
                bf16x8 kb = *reinterpret_cast<const bf16x8*>(&Ks[(j * 16 + lrow) * KP + quad * 8 + ks * 32]);
                sc[j] = __builtin_amdgcn_mfma_f32_16x16x32_bf16(aq[ks], kb, sc[j], 0, 0, 0);
            }

        #pragma unroll
        for (int rg = 0; rg < 4; rg++) {
            int row = q0 + w * 16 + quad * 4 + rg;
            float lacc = 0.f;
            #pragma unroll
            for (int j = 0; j < 4; j++) {
                float pval = __expf(sc[j][rg] * 0.125f);
                if (k0 + j * 16 + lrow > row) pval = 0.f;   // full causal mask
                Pw[(quad * 4 + rg) * KP + j * 16 + lrow] = f2bf(pval);
                lacc += pval;
            }
            l[rg] += lacc;
        }
        #pragma unroll
        for (int ks = 0; ks < 2; ks++) {
            bf16x8 pa = *reinterpret_cast<const bf16x8*>(&Pw[lrow * KP + quad * 8 + ks * 32]);
            #pragma unroll
            for (int jd = 0; jd < 4; jd++) {
                bf16x8 vb = *reinterpret_cast<const bf16x8*>(&Vs[(jd * 16 + lrow) * KP + quad * 8 + ks * 32]);
                of[jd] = __builtin_amdgcn_mfma_f32_16x16x32_bf16(pa, vb, of[jd], 0, 0, 0);
            }
        }
    }

    #pragma unroll
    for (int rg = 0; rg < 4; rg++) {
        float lv = l[rg];
        #pragma unroll
        for (int off = 1; off < 16; off <<= 1) lv += __shfl_xor(lv, off);
        float inv = 1.0f / lv;
        int row = q0 + w * 16 + quad * 4 + rg;
        unsigned short* Cr = CTX + ((size_t)(b * NHEADS + h) * SEQL + row) * DK;
        #pragma unroll
        for (int jd = 0; jd < 4; jd++) Cr[jd * 16 + lrow] = f2bf(of[jd][rg] * inv);
    }
}

// ---------------- O-projection GEMM, 128x64 tile, BK=64 (r9-proven) ----------
__global__ __launch_bounds__(256) void o_gemm(
    const unsigned short* __restrict__ Ag,   // CTX [b][h][s][d] bf16
    const unsigned short* __restrict__ Bg,   // Wob [1024][1024] bf16
    const float* __restrict__ bias, float* __restrict__ C)
{
    __shared__ __align__(16) unsigned short SM[12288];  // 24 KB
    unsigned short* As0 = SM;
    unsigned short* As1 = SM + 4096;
    unsigned short* Bs0 = SM + 8192;
    unsigned short* Bs1 = SM + 10240;

    const int t = threadIdx.x, lane = t & 63, wave = t >> 6;
    const int quad = lane >> 4, lrow = lane & 15;
    const int m0 = blockIdx.y * 128, n0 = blockIdx.x * 64;
    const int srow = lane >> 2;
    const int scol = (lane & 3) * 8;

    floatx4 acc[2][4];
    #pragma unroll
    for (int i = 0; i < 2; i++)
        #pragma unroll
        for (int j = 0; j < 4; j++) acc[i][j] = (floatx4){0.f,0.f,0.f,0.f};

    for (int k0 = 0; k0 < EMBED; k0 += 64) {
        const int hh = k0 >> 6;   // head for this K-slice
        __syncthreads();
        #pragma unroll
        for (int c = 0; c < 2; c++) {
            int tok = m0 + wave * 32 + c * 16 + srow;
            const unsigned short* as = Ag
                + ((size_t)((tok >> 11) * NHEADS + hh) * SEQL + (tok & (SEQL - 1))) * DK + scol;
            async16(&As0[wave * 1024 + c * 512], as);
            async16(&As1[wave * 1024 + c * 512], as + 32);
        }
        const unsigned short* bs = Bg + (size_t)(n0 + wave * 16 + srow) * EMBED + k0 + scol;
        async16(&Bs0[wave * 512], bs);
        async16(&Bs1[wave * 512], bs + 32);
        __syncthreads();

        #pragma unroll
        for (int ks = 0; ks < 2; ks++) {
            const unsigned short* Ab = ks ? As1 : As0;
            const unsigned short* Bb = ks ? Bs1 : Bs0;
            bf16x8 af[2], bfB[4];
            #pragma unroll
            for (int i = 0; i < 2; i++)
                af[i] = *reinterpret_cast<const bf16x8*>(&Ab[(wave * 32 + i * 16 + lrow) * 32 + quad * 8]);
            #pragma unroll
            for (int j = 0; j < 4; j++)
                bfB[j] = *reinterpret_cast<const bf16x8*>(&Bb[(j * 16 + lrow) * 32 + quad * 8]);
            #pragma unroll
            for (int i = 0; i < 2; i++)
                #pragma unroll
                for (int j = 0; j < 4; j++)
                    acc[i][j] = __builtin_amdgcn_mfma_f32_16x16x32_bf16(af[i], bfB[j], acc[i][j], 0, 0, 0);
        }
    }

    #pragma unroll
    for (int i = 0; i < 2; i++)
        #pragma unroll
        for (int rg = 0; rg < 4; rg++) {
            int row_g = m0 + wave * 32 + i * 16 + quad * 4 + rg;
            #pragma unroll
            for (int j = 0; j < 4; j++) {
                int col_g = n0 + j * 16 + lrow;
                C[(size_t)row_g * EMBED + col_g] = acc[i][j][rg] + bias[col_g];
            }
        }
}

// ---------------- launch ----------------
extern "C" void kernel_launch(void* const* d_in, const int* in_sizes, int n_in,
                              void* d_out, int out_size, void* d_ws, size_t ws_size,
                              hipStream_t stream) {
    const float* x    = (const float*)d_in[0];
    const float* cosT = (const float*)d_in[2];
    const float* sinT = (const float*)d_in[3];
    const float* Wq = (const float*)d_in[4];  const float* bq = (const float*)d_in[5];
    const float* Wk = (const float*)d_in[6];  const float* bk = (const float*)d_in[7];
    const float* Wv = (const float*)d_in[8];  const float* bv = (const float*)d_in[9];
    const float* Wo = (const float*)d_in[10]; const float* bo = (const float*)d_in[11];

    const size_t MB = 1024 * 1024;
    char* ws = (char*)d_ws;
    unsigned short* xb   = (unsigned short*)(ws);            //  8 MB
    unsigned short* Wqkv = (unsigned short*)(ws +  8 * MB);  //  6 MB
    unsigned short* Wob  = (unsigned short*)(ws + 14 * MB);  //  2 MB
    unsigned short* Qg   = (unsigned short*)(ws + 16 * MB);  //  8 MB [b][h][s][d]
    unsigned short* Kg   = (unsigned short*)(ws + 24 * MB);  //  8 MB [b][h][s][d]
    unsigned short* Vt   = (unsigned short*)(ws + 32 * MB);  //  8 MB [b][h][d][s]
    unsigned short* CTXb = (unsigned short*)(ws + 40 * MB);  //  8 MB [b][h][s][d]

    convert_pack<<<8192, 256, 0, stream>>>(x, Wq, Wk, Wv, Wo, xb, Wqkv, Wob);

    dim3 qkv_grid(3 * EMBED / 128, NTOK / 128);   // (24, 32) = 768
    qkv_gemm<<<qkv_grid, 256, 0, stream>>>(xb, Wqkv, bq, bk, bv, cosT, sinT, Qg, Kg, Vt);

    dim3 attn_grid(SEQL / 128, NHEADS, BATCH);    // (16, 16, 2) = 512
    attn_mfma<<<attn_grid, 512, 0, stream>>>(Qg, Kg, Vt, CTXb);

    dim3 o_grid(EMBED / 64, NTOK / 128);          // (16, 32) = 512
    o_gemm<<<o_grid, 256, 0, stream>>>(CTXb, Wob, bo, (float*)d_out);
}